// Round 15
// baseline (7144.135 us; speedup 1.0000x reference)
//
#include <hip/hip_runtime.h>
#include <hip/hip_fp16.h>

typedef _Float16 f16x8 __attribute__((ext_vector_type(8)));
typedef float f32x4 __attribute__((ext_vector_type(4)));
typedef float f32x16 __attribute__((ext_vector_type(16)));
typedef unsigned short u16;
typedef unsigned int u32;

#define T_STEPS 512
#define BATCH   512
#define DTF     0.01f

// workspace layout (bytes)
#define CTR_OFF 0
#define CTR_SZ  1048576                     // slot counters + per-(g,slot) flags
#define WB_OFF  (CTR_OFF + CTR_SZ)
#define WB_SZ   (32*200*384*2)              // 4,915,200  [slice][mat*100+unit][384 u16] 32x32 B-frags
#define WRB_OFF (WB_OFF + WB_SZ)
#define WRB_SZ  (4*24*64*8*2)               // 98,304     W_r f16 B-frag layout (16x16x32)
#define ST_OFF  (WRB_OFF + WRB_SZ)
#define ST_SZ   (2*8*64*1536*2)             // 3,145,728  state [buf][g][row 64][k' 1536] f16
#define WS_NEED (ST_OFF + ST_SZ)

#define MFMA32(a,b,c) __builtin_amdgcn_mfma_f32_32x32x16_f16((a),(b),(c),0,0,0)
#define MFMA16(a,b,c) __builtin_amdgcn_mfma_f32_16x16x32_f16((a),(b),(c),0,0,0)

// Intra-XCD acquire: L2 is the coherence point, L1 write-through => L1-only
// invalidate; one wave per CU. [Verified rounds 3-14.]
#define ACQUIRE_L1() asm volatile("s_waitcnt vmcnt(0)\n\tbuffer_inv sc0" ::: "memory")

__device__ __forceinline__ u16 f2h(float f){ _Float16 h = (_Float16)f; return *reinterpret_cast<u16*>(&h); }

__device__ __forceinline__ float ftanh(float x){
  float a = fminf(fmaxf(x, -12.f), 12.f);
  float e = __expf(2.f * a);
  return 1.f - 2.f * __builtin_amdgcn_rcpf(e + 1.f);
}

// ---- 32x32x16 fragment maps [verified r12: absmax 0.03125] ----
// A (32x16): lane holds A[l&31][(l>>5)*8 + e]
// B (16x32): lane holds B[(l>>5)*8 + e][l&31]
// C (32x32): lane covers col = l&31, rows = (e&3) + 8*(e>>2) + 4*(l>>5)
//
// LDS B storage per (slice s, mat m2, unit u): 48 granules of 16B, XOR-swizzled
// (balanced: 6 granules per bank-quad). Lanes col>=24 alias col-24 (broadcast).

__global__ __launch_bounds__(64) void prep_weights(const float* __restrict__ Wh,
                                                   const float* __restrict__ Wp,
                                                   const float* __restrict__ Wr,
                                                   u16* __restrict__ Wb, u16* __restrict__ Wrb){
  int b = blockIdx.x, l = threadIdx.x;
  if (b < 6400){
    int s = b / 200, r2 = b % 200;
    int m2 = r2 / 100, u = r2 % 100;
    if (l < 48){
      int c = l >> 1, kh = l & 1;
      int gg = c*2 + kh, rr = gg >> 3, cc = gg & 7;
      size_t dst = (size_t)s*76800 + (size_t)(m2*100 + u)*384 + (size_t)rr*64 + (size_t)((cc ^ (rr & 7))*8);
      const float* W = m2 ? Wp : Wh;
      const float* src = W + (size_t)(s*24 + c)*1600 + u*16 + kh*8;
      f16x8 o;
#pragma unroll
      for (int e = 0; e < 8; ++e) o[e] = (_Float16)src[e];
      *reinterpret_cast<f16x8*>(Wb + dst) = o;
    }
  } else {
    int b2 = b - 6400;                      // 0..95  (W_r, 16x16x32 B-frags)
    int nt = b2 / 24, kt = b2 % 24;
    int c = nt*16 + (l & 15), k = kt*32 + (l >> 4)*8;
    const float* src = Wr + (size_t)c*768 + k;
    f16x8 o;
#pragma unroll
    for (int e = 0; e < 8; ++e) o[e] = (_Float16)src[e];
    *reinterpret_cast<f16x8*>(Wrb + ((size_t)b2*64 + l)*8) = o;
  }
}

// grid = 256 x 256. Group = PHYSICAL XCD (HW_REG_XCC_ID), slot via atomicAdd:
// 32 blocks/XCD. Slot s owns out-cols [s*24,+24) of BOTH W_h/W_p.
// Wave (m = w&1, p = w>>1): m-tile rows [m*32,+32), K-half p. 32x32x16 MFMA
// (r12) + e-major conflict-free reduce scratch (r14). THIS ROUND: publish =
// per-slot relaxed flag STORE (no RMW) + 32-lane flag poll — removes the
// 32-way contended fetch_add on one MALL dword (r3-vs-r4/r6 cross-round
// evidence: independent flags beat the shared counter by ~2ms even with 2x
// the hops). flag >= t  <=>  slot finished step t-1 (tile t written, tile
// t-1 reads drained) — identical invariant to the counter version.
__global__ __launch_bounds__(256, 1) void rnn_main(
    const float* __restrict__ x, const float* __restrict__ bh_g, const float* __restrict__ bp_g,
    const float* __restrict__ br_g, const u16* __restrict__ Wb, const u16* __restrict__ Wrb,
    u16* __restrict__ st, u32* __restrict__ ctr, float* __restrict__ out)
{
  extern __shared__ u16 smem[];             // [0,153600): B-frags; [153600,161792): reduce scratch
  __shared__ int s_dead, s_slot, s_xcd;

  const int tid = threadIdx.x;
  if (tid == 0){
    s_dead = 0;
    u32 xcd;
    asm volatile("s_getreg_b32 %0, hwreg(HW_REG_XCC_ID)" : "=s"(xcd));
    xcd &= 7u;
    s_xcd  = (int)xcd;
    s_slot = (int)atomicAdd(ctr + xcd, 1u); // device-scope, ctr pre-zeroed
  }
  __syncthreads();
  const int gx = s_xcd;
  const int s  = s_slot;
  if (s >= 32) return;

  const int c0   = s * 24;
  const int l    = tid & 63;
  const int w    = tid >> 6;
  const int m    = w & 1;                   // m-tile (rows m*32..+32)
  const int p    = w >> 1;                  // K-half
  const int colW = l & 31;                  // C col / A row-in-tile
  const int khB  = l >> 5;                  // k-half within unit
  const bool validC = (colW < 24);
  const int colB = validC ? colW : colW - 24;
  const int gran = colB*2 + khB;
  const int grr  = gran >> 3, gcc = gran & 7;
  const int bfi  = grr*8 + (gcc ^ (grr & 7));   // f16x8 index within a 768B unit-block

  // per-(g,slot) monotonic flags: FL[s*32], 128B stride  [r3/r8 primitive]
  u32* FL = ctr + 2048 + (size_t)gx*16384;

  // stage packed weight slice global -> LDS (153.6 KB)
  {
    const float4* srcw = reinterpret_cast<const float4*>(Wb + (size_t)s*76800);
    float4* dst = reinterpret_cast<float4*>(smem);
    for (int i = tid; i < 9600; i += 256) dst[i] = srcw[i];
  }
  __syncthreads();

  const f16x8* WBp = reinterpret_cast<const f16x8*>(smem);
  float* scr = reinterpret_cast<float*>(smem + 76800);   // 8KB reduce scratch, e-major

  // x-unit B-frags (units 0..3, both mats) held permanently in registers (p==0)
  f16x8 xbh[4], xbp[4];
  if (p == 0){
#pragma unroll
    for (int u = 0; u < 4; ++u){ xbh[u] = WBp[u*48 + bfi]; xbp[u] = WBp[(100+u)*48 + bfi]; }
  }

  const int dcol = c0 + (validC ? colW : 0);
  const float bhv = bh_g[dcol];
  const float bpv = bp_g[dcol];

  float hz[16] = {}, hy[16] = {};           // fp32 master state (p==0 waves)

  // wave0 wait: lane i<32 polls slot-i flag (independent lines, no RMW queue);
  // monotonic => uniform exit; s_sleep backoff; timeout bails (no hang).
  auto wait_flags = [&](u32 tgt){
    if (s_dead) return;
    long spins = 0;
    for (;;){
      bool ok = true;
      if (l < 32) ok = (__hip_atomic_load(FL + l*32, __ATOMIC_RELAXED, __HIP_MEMORY_SCOPE_AGENT) >= tgt);
      if (__all(ok)) break;
      __builtin_amdgcn_s_sleep(1);
      if (++spins > 1000000L){ if (l == 0) s_dead = 1; break; }
    }
  };

#define STATE_LOOP(U0c, NUc) do { \
    f16x8 av[4]; \
    _Pragma("unroll") \
    for (int i = 0; i < 4; ++i) av[i] = *reinterpret_cast<const f16x8*>(stb + (size_t)((U0c)-4+i)*16); \
    _Pragma("unroll") \
    for (int i = 0; i < (NUc); ++i){ \
      f16x8 a = av[i & 3]; \
      if (i + 4 < (NUc)) av[i & 3] = *reinterpret_cast<const f16x8*>(stb + (size_t)((U0c)+i)*16); \
      f16x8 bh8 = WBp[((U0c)+i)*48 + bfi]; \
      f16x8 bp8 = WBp[(100+(U0c)+i)*48 + bfi]; \
      f16x8 asq = a*a; \
      accH = MFMA32(a,   bh8, accH); \
      accP = MFMA32(asq, bp8, accP); \
    } } while (0)

#pragma unroll 1
  for (int t = 0; t < T_STEPS; ++t){
    f32x16 accH = {}, accP = {};

    // x contribution (units 0..3): independent of the tile — done pre-wait
    if (p == 0){
      const float* xb = x + ((size_t)t*BATCH + gx*64 + m*32 + colW)*64 + khB*8;
#pragma unroll
      for (int u = 0; u < 4; ++u){
        const float4 uu = *reinterpret_cast<const float4*>(xb + u*16);
        const float4 vv = *reinterpret_cast<const float4*>(xb + u*16 + 4);
        f16x8 xa8, xs8;
        xa8[0]=(_Float16)uu.x; xa8[1]=(_Float16)uu.y; xa8[2]=(_Float16)uu.z; xa8[3]=(_Float16)uu.w;
        xa8[4]=(_Float16)vv.x; xa8[5]=(_Float16)vv.y; xa8[6]=(_Float16)vv.z; xa8[7]=(_Float16)vv.w;
        xs8[0]=(_Float16)(uu.x*uu.x); xs8[1]=(_Float16)(uu.y*uu.y); xs8[2]=(_Float16)(uu.z*uu.z); xs8[3]=(_Float16)(uu.w*uu.w);
        xs8[4]=(_Float16)(vv.x*vv.x); xs8[5]=(_Float16)(vv.y*vv.y); xs8[6]=(_Float16)(vv.z*vv.z); xs8[7]=(_Float16)(vv.w*vv.w);
        accH = MFMA32(xa8, xbh[u], accH);
        accP = MFMA32(xs8, xbp[u], accP);
      }
    }

    if (w == 0){
      if (t > 0) wait_flags((u32)t);        // all slots finished step t-1
      ACQUIRE_L1();
    }
    __syncthreads();
    if (s_dead) break;

    // state A-frags: lane reads 16B at row = m*32+colW, k-offset khB*8 (plain layout)
    const u16* stb = st + ((((size_t)(t&1)*8 + gx)*64) + m*32 + colW)*1536 + khB*8;
    if (p == 0) STATE_LOOP(4, 46); else STATE_LOOP(50, 50);

    // cross-wave K-half reduce via e-major scratch (conflict-free, r14).
    if (p == 1){
#pragma unroll
      for (int e = 0; e < 16; ++e) scr[e*128 + m*64 + l] = accH[e];
    }
    __syncthreads();
    if (p == 0){
#pragma unroll
      for (int e = 0; e < 16; ++e) accH[e] += scr[e*128 + m*64 + l];
    }
    __syncthreads();
    if (p == 1){
#pragma unroll
      for (int e = 0; e < 16; ++e) scr[e*128 + m*64 + l] = accP[e];
    }
    __syncthreads();
    if (p == 0){
#pragma unroll
      for (int e = 0; e < 16; ++e) accP[e] += scr[e*128 + m*64 + l];
    }

    // update + store (waves 0/1 only; lane covers col=colW, 16 rows)
    if (p == 0){
      u16* wtb = st + (((size_t)((t+1)&1)*8 + gx)*64)*1536;
#pragma unroll
      for (int e = 0; e < 16; ++e){
        float hv = ftanh(accH[e] + bhv);
        float pv = ftanh(accP[e] + bpv);
        hz[e] += DTF * (hv + pv);
        hy[e] += DTF * hz[e];
        if (validC){
          int row = m*32 + (e & 3) + 8*(e >> 2) + 4*khB;
          wtb[(size_t)row*1536 + dcol]       = f2h(hz[e]);
          wtb[(size_t)row*1536 + 768 + dcol] = f2h(hy[e]);
        }
      }
      asm volatile("s_waitcnt vmcnt(0)" ::: "memory");   // stores visible in XCD L2
    }
    __syncthreads();
    if (tid == 0)
      __hip_atomic_store(FL + s*32, (u32)(t+1), __ATOMIC_RELAXED, __HIP_MEMORY_SCOPE_AGENT);
  }
#undef STATE_LOOP

  // final projection: out = hy @ W_r^T + b_r, slot-0 block (16x16x32 path)
  if (s == 0 && !s_dead){
    if (w == 0){ wait_flags((u32)T_STEPS); ACQUIRE_L1(); }
    __syncthreads();
    if (!s_dead){
      const int colL = l & 15, kq4 = l >> 4;
      const u16* hyb = st + (((size_t)gx*64) + w*16 + colL)*1536 + 768 + kq4*8;  // buf0
      const f16x8* Wr8 = reinterpret_cast<const f16x8*>(Wrb);
      f32x4 oc[4] = {};
#pragma unroll
      for (int kt = 0; kt < 24; ++kt){
        f16x8 a = *reinterpret_cast<const f16x8*>(hyb + (size_t)kt*32);
#pragma unroll
        for (int nt = 0; nt < 4; ++nt)
          oc[nt] = MFMA16(a, Wr8[(nt*24 + kt)*64 + l], oc[nt]);
      }
      const int rowC = w*16 + kq4*4;
#pragma unroll
      for (int nt = 0; nt < 4; ++nt){
        float bb = br_g[nt*16 + colL];
#pragma unroll
        for (int e = 0; e < 4; ++e)
          out[(size_t)(gx*64 + rowC + e)*64 + nt*16 + colL] = oc[nt][e] + bb;
      }
    }
  }
}

extern "C" void kernel_launch(void* const* d_in, const int* in_sizes, int n_in,
                              void* d_out, int out_size, void* d_ws, size_t ws_size,
                              hipStream_t stream) {
  const float* x  = (const float*)d_in[0];
  const float* Wh = (const float*)d_in[1];
  const float* bh = (const float*)d_in[2];
  const float* Wp = (const float*)d_in[3];
  const float* bp = (const float*)d_in[4];
  const float* Wr = (const float*)d_in[5];
  const float* br = (const float*)d_in[6];
  float* out = (float*)d_out;

  if (ws_size < (size_t)WS_NEED) return;    // loud failure: output stays zero
  char* ws = (char*)d_ws;

  u16* Wb  = (u16*)(ws + WB_OFF);
  u16* Wrb = (u16*)(ws + WRB_OFF);
  u16* st  = (u16*)(ws + ST_OFF);
  u32* ctr = (u32*)(ws + CTR_OFF);

  hipMemsetAsync(ws + CTR_OFF, 0, CTR_SZ, stream);   // slot counters + flags
  hipMemsetAsync(ws + ST_OFF,  0, ST_SZ,  stream);   // zero initial state (t=0)

  prep_weights<<<6496, 64, 0, stream>>>(Wh, Wp, Wr, Wb, Wrb);

  (void)hipFuncSetAttribute(reinterpret_cast<const void*>(rnn_main),
                            hipFuncAttributeMaxDynamicSharedMemorySize, 161792);
  rnn_main<<<256, 256, 161792, stream>>>(x, bh, bp, br, Wb, Wrb, st, ctr, out);
}